// Round 9
// baseline (152.485 us; speedup 1.0000x reference)
//
#include <hip/hip_runtime.h>

#define D  128   // EMB
#define KN 128   // K_N
#define NB 16    // batch rows per block
#define LOG2E 1.44269504088896340736f

typedef float f32x4  __attribute__((ext_vector_type(4)));
typedef float f32x16 __attribute__((ext_vector_type(16)));
typedef short s16x8  __attribute__((ext_vector_type(8)));   // 8 bf16 (4 VGPR)

__device__ __forceinline__ float negexp(float v) {              // e^{-v}
    return __builtin_amdgcn_exp2f(v * -LOG2E);
}
__device__ __forceinline__ float sigf(float x) {                // sigmoid
    return __builtin_amdgcn_rcpf(1.0f + negexp(x));
}
__device__ __forceinline__ unsigned short f2bf(float f) {       // fp32->bf16 RNE
    unsigned u = __float_as_uint(f);
    return (unsigned short)((u + 0x7fffu + ((u >> 16) & 1u)) >> 16);
}
__device__ __forceinline__ s16x8 pack8(float4 a, float4 b) {
    s16x8 r;
    r[0]=(short)f2bf(a.x); r[1]=(short)f2bf(a.y); r[2]=(short)f2bf(a.z); r[3]=(short)f2bf(a.w);
    r[4]=(short)f2bf(b.x); r[5]=(short)f2bf(b.y); r[6]=(short)f2bf(b.z); r[7]=(short)f2bf(b.w);
    return r;
}
__device__ __forceinline__ s16x8 pack8abs(float4 a, float4 b) {
    s16x8 r;
    r[0]=(short)f2bf(fabsf(a.x)); r[1]=(short)f2bf(fabsf(a.y)); r[2]=(short)f2bf(fabsf(a.z)); r[3]=(short)f2bf(fabsf(a.w));
    r[4]=(short)f2bf(fabsf(b.x)); r[5]=(short)f2bf(fabsf(b.y)); r[6]=(short)f2bf(fabsf(b.z)); r[7]=(short)f2bf(fabsf(b.w));
    return r;
}

// phase-B core: 2 elements (k=2l,2l+1) of one (b,e)
#define CORE(EA1, EA2, T, PZ, A0, A1) do {                                   \
    float x0_ = fmaf((EA1), (T).x, 1.0f);                                    \
    float x1_ = fmaf((EA1), (T).y, 1.0f);                                    \
    float y0_ = fmaf((EA2), (T).z, 1.0f);                                    \
    float y1_ = fmaf((EA2), (T).w, 1.0f);                                    \
    (A0) = fmaf((y0_ - x0_) * (PZ), __builtin_amdgcn_rcpf(x0_ * y0_), (A0)); \
    (A1) = fmaf((y1_ - x1_) * (PZ), __builtin_amdgcn_rcpf(x1_ * y1_), (A1)); \
} while (0)

// tables write: exp(-(acc+bias)) into interleaved TAB layout
//   TABf[e*256 + (k>>1)*4 + (k&1) + (0|2)]  (32x32 C-layout per m74)
#define TWRITE(IDX, ACC) {                                                    \
    const int slot_ = ((IDX) < 16) ? 0 : 2;                                   \
    const float* bias_ = ((IDX) < 16) ? b1 : b2;                              \
    const int k_ = ((IDX) & 3) * 32 + l31;                                    \
    const int kof_ = ((k_ >> 1) << 2) + (k_ & 1) + slot_;                     \
    _Pragma("unroll")                                                         \
    for (int r = 0; r < 16; ++r) {                                            \
        int e_ = (((IDX) >> 2) & 3) * 32 + (r & 3) + ((r >> 2) << 3) + (g32 << 2); \
        TABf[e_ * 256 + kof_] = negexp(ACC[r] + bias_[e_]);                   \
    } }

__global__ __launch_bounds__(1024, 4) void fused_kernel(
    const int* __restrict__ stu_id, const int* __restrict__ exer_id,
    const float* __restrict__ kq,
    const float* __restrict__ stu_q, const float* __restrict__ exer_k,
    const float* __restrict__ stu_v, const float* __restrict__ exer_v,
    const float* __restrict__ kn,
    const float* __restrict__ W1, const float* __restrict__ b1,
    const float* __restrict__ W2, const float* __restrict__ b2,
    const float* __restrict__ W3, const float* __restrict__ b3,
    float* __restrict__ out, int B)
{
    // LDS map (155648 B = 9728 float4):
    //   [0,131072)       phase A: KNs(32K)|W1s(32K)|W2s(32K) bf16, XOR-swizzled
    //                    phase B: TAB fp32[e][k-interleaved]; epilogue: RED (alias)
    //   [131072,147456)  EAf: Ea1/Ea2 interleaved, float ofs b*256 + 2e + {0,1}
    //   [147456,155648)  PZf: pz, float ofs r*128 + e
    __shared__ float4 smem4[9728];
    float* TABf = (float*)smem4;
    float* EAf  = TABf + 32768;
    float* PZf  = EAf + 4096;
    char* KNs_base = (char*)smem4;
    char* W1s_base = KNs_base + 32768;
    char* W2s_base = KNs_base + 65536;

    const int tid  = threadIdx.x;
    const int b0   = blockIdx.x * NB;
    const int lane = tid & 63, wid = tid >> 6;     // 16 waves
    const int l31 = lane & 31, g32 = lane >> 5;
    const int l15 = lane & 15, g16 = lane >> 4;
    const int bmax = B - 1;

    // ---- waves 0-7: issue scattered prep gathers FIRST (T14 latency hide) ----
    float4 ga[8], ge[8];
    if (wid < 8) {
        int bl = b0 + l15; bl = bl <= bmax ? bl : bmax;
        const int sid_l = stu_id[bl], eid_l = exer_id[bl];
        #pragma unroll
        for (int q = 0; q < 4; ++q) {
            int d = q * 32 + g16 * 8;
            const float4* pa = (const float4*)(stu_v + (size_t)sid_l * D + d);
            ga[2*q] = pa[0]; ga[2*q+1] = pa[1];
            const float4* pe = (const float4*)(exer_v + (size_t)eid_l * D + d);
            ge[2*q] = pe[0]; ge[2*q+1] = pe[1];
        }
    }

    // ---- stage kn, |W1b|, |W2b| as bf16 (pack ONCE), row 256B, XOR-swizzled ----
    for (int i = tid; i < 128 * 16; i += 1024) {   // 2 iters/thread
        int row = i >> 4, c = i & 15;
        int byt = row * 256 + (((c << 4)) ^ ((row & 7) << 4));
        const float4* sk = (const float4*)(kn + (size_t)row * D + c * 8);
        *(s16x8*)(KNs_base + byt) = pack8(sk[0], sk[1]);
        const float4* s1 = (const float4*)(W1 + (size_t)row * (2 * D) + D + c * 8);
        *(s16x8*)(W1s_base + byt) = pack8abs(s1[0], s1[1]);
        const float4* s2 = (const float4*)(W2 + (size_t)row * (2 * D) + D + c * 8);
        *(s16x8*)(W2s_base + byt) = pack8abs(s2[0], s2[1]);
    }
    __syncthreads();

    // ---- tables GEMM: 32 tiles / 16 waves = 2 (same set+et, kt pair), A hoisted ----
    f32x16 t0acc = {0}, t1acc = {0};
    const int idx0 = 2 * wid;                      // tile ids idx0, idx0+1
    {
        const char* Wsb = (idx0 < 16) ? W1s_base : W2s_base;
        const int er = (((idx0 >> 2) & 3)) * 32 + l31;
        const int eswz = (er & 7) << 4;
        const int kr0 = (idx0 & 3) * 32 + l31;     // idx0&3 in {0,2}
        const int kr1 = kr0 + 32;
        const int kswz = (l31 & 7) << 4;
        #pragma unroll
        for (int q = 0; q < 8; ++q) {
            int dby = q * 32 + g32 * 16;
            s16x8 a_ = *(const s16x8*)(Wsb + er * 256 + (dby ^ eswz));
            s16x8 f0 = *(const s16x8*)(KNs_base + kr0 * 256 + (dby ^ kswz));
            s16x8 f1 = *(const s16x8*)(KNs_base + kr1 * 256 + (dby ^ kswz));
            t0acc = __builtin_amdgcn_mfma_f32_32x32x16_bf16(a_, f0, t0acc, 0, 0, 0);
            t1acc = __builtin_amdgcn_mfma_f32_32x32x16_bf16(a_, f1, t1acc, 0, 0, 0);
        }
    }

    // ---- role split: waves 0-7 prep GEMM (e-tile = wid); waves 8-15 PZ ----
    if (wid < 8) {
        const int erow = wid * 16 + l15;
        f32x4 accS = {0, 0, 0, 0}, accE = {0, 0, 0, 0};
        #pragma unroll
        for (int q = 0; q < 4; ++q) {
            int d = q * 32 + g16 * 8;
            const float4* pb = (const float4*)(W1 + (size_t)erow * (2 * D) + d);
            accS = __builtin_amdgcn_mfma_f32_16x16x32_bf16(
                pack8(ga[2*q], ga[2*q+1]), pack8abs(pb[0], pb[1]), accS, 0, 0, 0);
            const float4* pc = (const float4*)(W2 + (size_t)erow * (2 * D) + d);
            accE = __builtin_amdgcn_mfma_f32_16x16x32_bf16(
                pack8(ge[2*q], ge[2*q+1]), pack8abs(pc[0], pc[1]), accE, 0, 0, 0);
        }
        #pragma unroll
        for (int r = 0; r < 4; ++r) {              // lane holds b=g16*4+r, e=erow
            int bi = g16 * 4 + r;
            int eo = bi * 256 + 2 * erow;
            EAf[eo]     = negexp(accS[r]);
            EAf[eo + 1] = negexp(accE[r]);
        }
    } else {
        const int w2 = wid - 8;
        #pragma unroll
        for (int rr = 0; rr < 2; ++rr) {           // 2 b-rows per wave
            int r = 2 * w2 + rr;
            int b = b0 + r; b = b <= bmax ? b : bmax;
            int sid = stu_id[b], eid = exer_id[b]; // wave-uniform -> s_load
            float2 sq = *(const float2*)(stu_q + (size_t)sid * D + 2 * lane);
            float2 ek = *(const float2*)(exer_k + (size_t)eid * D + 2 * lane);
            float2 w3 = *(const float2*)(W3 + 2 * lane);
            float2 z;
            z.x = sigf(sq.x * ek.x) * fabsf(w3.x);
            z.y = sigf(sq.y * ek.y) * fabsf(w3.y);
            *(float2*)(PZf + r * D + 2 * lane) = z;
        }
    }
    __syncthreads();   // all staged-LDS reads done -> TAB may overwrite

    TWRITE(idx0, t0acc) TWRITE(idx0 + 1, t1acc)
    __syncthreads();   // TAB/EA/PZ ready

    // ---------------- Phase B: wave owns e in [8*wid, 8*wid+8), lane owns k-pair ----
    const float4* TAB4 = (const float4*)TABf;
    const float4* EA4  = (const float4*)EAf;
    const float2* PZ2  = (const float2*)PZf;

    float2 acc[16];
    #pragma unroll
    for (int r = 0; r < 16; ++r) acc[r] = make_float2(0.f, 0.f);

    #pragma unroll
    for (int jj = 0; jj < 4; ++jj) {
        const int e0 = wid * 8 + 2 * jj;
        const int jg = wid * 4 + jj;
        float4 t0 = TAB4[e0 * 64 + lane];          // per-lane b128
        float4 t1 = TAB4[(e0 + 1) * 64 + lane];
        #pragma unroll
        for (int r = 0; r < 16; ++r) {
            float4 eA = EA4[r * 64 + jg];          // wave-uniform LDS broadcast
            float2 zA = PZ2[r * 64 + jg];
            CORE(eA.x, eA.y, t0, zA.x, acc[r].x, acc[r].y);
            CORE(eA.z, eA.w, t1, zA.y, acc[r].x, acc[r].y);
        }
    }
    __syncthreads();                     // all TAB reads done -> RED may alias

    float2* RED = (float2*)TABf;         // [wave][row][lane] = 128 KB
    #pragma unroll
    for (int r = 0; r < 16; ++r)
        RED[(wid * 16 + r) * 64 + lane] = acc[r];
    __syncthreads();

    // ---- cross-wave reduce + epilogue: wave w handles row w ----
    {
        const int r = wid, b = b0 + r;
        float2 s = make_float2(0.f, 0.f);
        #pragma unroll
        for (int w = 0; w < 16; ++w) {
            float2 p = RED[(w * 16 + r) * 64 + lane];
            s.x += p.x; s.y += p.y;
        }
        const float b3v = b3[0];
        float o0 = sigf(s.x + b3v), o1 = sigf(s.y + b3v);
        float num = 0.f, den = 0.f;
        if (b < B) {
            float2 kqv = *(const float2*)(kq + (size_t)b * D + 2 * lane);
            num = fmaf(o0, kqv.x, o1 * kqv.y); den = kqv.x + kqv.y;
        }
        #pragma unroll
        for (int off = 32; off > 0; off >>= 1) {
            num += __shfl_xor(num, off); den += __shfl_xor(den, off);
        }
        if (lane == 0 && b < B) out[b] = num / den;
    }
}

// ---------------------------------------------------------------------------
extern "C" void kernel_launch(void* const* d_in, const int* in_sizes, int n_in,
                              void* d_out, int out_size, void* d_ws, size_t ws_size,
                              hipStream_t stream)
{
    const int*   stu_id      = (const int*)  d_in[0];
    const int*   exer_id     = (const int*)  d_in[1];
    const float* kq          = (const float*)d_in[2];
    const float* student_q   = (const float*)d_in[3];
    const float* exercise_k  = (const float*)d_in[4];
    const float* student_v   = (const float*)d_in[5];
    const float* exercise_v  = (const float*)d_in[6];
    const float* knowledge_v = (const float*)d_in[7];
    const float* W1 = (const float*)d_in[8];
    const float* b1 = (const float*)d_in[9];
    const float* W2 = (const float*)d_in[10];
    const float* b2 = (const float*)d_in[11];
    const float* W3 = (const float*)d_in[12];
    const float* b3 = (const float*)d_in[13];
    float* out = (float*)d_out;
    const int B = in_sizes[0];

    int nblk = (B + NB - 1) / NB;
    fused_kernel<<<nblk, 1024, 0, stream>>>(
        stu_id, exer_id, kq, student_q, exercise_k, student_v, exercise_v,
        knowledge_v, W1, b1, W2, b2, W3, b3, out, B);
}

// Round 10
// 148.520 us; speedup vs baseline: 1.0267x; 1.0267x over previous
//
#include <hip/hip_runtime.h>

#define D  128   // EMB
#define KN 128   // K_N
#define NB 16    // batch rows per block
#define LOG2E 1.44269504088896340736f

typedef float f32x4  __attribute__((ext_vector_type(4)));
typedef float f32x16 __attribute__((ext_vector_type(16)));
typedef short s16x8  __attribute__((ext_vector_type(8)));   // 8 bf16 (4 VGPR)

__device__ __forceinline__ float negexp(float v) {              // e^{-v}
    return __builtin_amdgcn_exp2f(v * -LOG2E);
}
__device__ __forceinline__ float sigf(float x) {                // sigmoid
    return __builtin_amdgcn_rcpf(1.0f + negexp(x));
}
__device__ __forceinline__ unsigned short f2bf(float f) {       // fp32->bf16 RNE
    unsigned u = __float_as_uint(f);
    return (unsigned short)((u + 0x7fffu + ((u >> 16) & 1u)) >> 16);
}
__device__ __forceinline__ s16x8 pack8(float4 a, float4 b) {
    s16x8 r;
    r[0]=(short)f2bf(a.x); r[1]=(short)f2bf(a.y); r[2]=(short)f2bf(a.z); r[3]=(short)f2bf(a.w);
    r[4]=(short)f2bf(b.x); r[5]=(short)f2bf(b.y); r[6]=(short)f2bf(b.z); r[7]=(short)f2bf(b.w);
    return r;
}
__device__ __forceinline__ s16x8 pack8abs(float4 a, float4 b) {
    s16x8 r;
    r[0]=(short)f2bf(fabsf(a.x)); r[1]=(short)f2bf(fabsf(a.y)); r[2]=(short)f2bf(fabsf(a.z)); r[3]=(short)f2bf(fabsf(a.w));
    r[4]=(short)f2bf(fabsf(b.x)); r[5]=(short)f2bf(fabsf(b.y)); r[6]=(short)f2bf(fabsf(b.z)); r[7]=(short)f2bf(fabsf(b.w));
    return r;
}

// phase-B core: 2 elements (k=2l,2l+1) of one (b,e)
#define CORE(EA1, EA2, T, PZ, A0, A1) do {                                   \
    float x0_ = fmaf((EA1), (T).x, 1.0f);                                    \
    float x1_ = fmaf((EA1), (T).y, 1.0f);                                    \
    float y0_ = fmaf((EA2), (T).z, 1.0f);                                    \
    float y1_ = fmaf((EA2), (T).w, 1.0f);                                    \
    (A0) = fmaf((y0_ - x0_) * (PZ), __builtin_amdgcn_rcpf(x0_ * y0_), (A0)); \
    (A1) = fmaf((y1_ - x1_) * (PZ), __builtin_amdgcn_rcpf(x1_ * y1_), (A1)); \
} while (0)

// tables write: exp(-(acc+bias)) into interleaved TAB layout
//   TABf[e*256 + (k>>1)*4 + (k&1) + (0|2)]  (32x32 C-layout per m74)
#define TWRITE(IDX, ACC) {                                                    \
    const int slot_ = ((IDX) < 16) ? 0 : 2;                                   \
    const float* bias_ = ((IDX) < 16) ? b1 : b2;                              \
    const int k_ = ((IDX) & 3) * 32 + l31;                                    \
    const int kof_ = ((k_ >> 1) << 2) + (k_ & 1) + slot_;                     \
    _Pragma("unroll")                                                         \
    for (int r = 0; r < 16; ++r) {                                            \
        int e_ = (((IDX) >> 2) & 3) * 32 + (r & 3) + ((r >> 2) << 3) + (g32 << 2); \
        TABf[e_ * 256 + kof_] = negexp(ACC[r] + bias_[e_]);                   \
    } }

__global__ __launch_bounds__(1024) void fused_kernel(
    const int* __restrict__ stu_id, const int* __restrict__ exer_id,
    const float* __restrict__ kq,
    const float* __restrict__ stu_q, const float* __restrict__ exer_k,
    const float* __restrict__ stu_v, const float* __restrict__ exer_v,
    const float* __restrict__ kn,
    const float* __restrict__ W1, const float* __restrict__ b1,
    const float* __restrict__ W2, const float* __restrict__ b2,
    const float* __restrict__ W3, const float* __restrict__ b3,
    float* __restrict__ out, int B)
{
    // LDS map (155648 B = 9728 float4):
    //   [0,131072)       phase A: KNs(32K)|W1s(32K)|W2s(32K) bf16, XOR-swizzled
    //                    phase B: TAB fp32[e][k-interleaved]; epilogue: RED (alias)
    //   [131072,147456)  EAf: Ea1/Ea2 interleaved, float ofs b*256 + 2e + {0,1}
    //   [147456,155648)  PZf: pz, float ofs r*128 + e
    __shared__ float4 smem4[9728];
    float* TABf = (float*)smem4;
    float* EAf  = TABf + 32768;
    float* PZf  = EAf + 4096;
    char* KNs_base = (char*)smem4;
    char* W1s_base = KNs_base + 32768;
    char* W2s_base = KNs_base + 65536;

    const int tid  = threadIdx.x;
    const int b0   = blockIdx.x * NB;
    const int lane = tid & 63, wid = tid >> 6;     // 16 waves
    const int l31 = lane & 31, g32 = lane >> 5;
    const int l15 = lane & 15, g16 = lane >> 4;
    const int bmax = B - 1;

    // ---- stage kn, |W1b|, |W2b| as bf16 (pack ONCE), row 256B, XOR-swizzled ----
    for (int i = tid; i < 128 * 16; i += 1024) {   // 2 iters/thread
        int row = i >> 4, c = i & 15;
        int byt = row * 256 + (((c << 4)) ^ ((row & 7) << 4));
        const float4* sk = (const float4*)(kn + (size_t)row * D + c * 8);
        *(s16x8*)(KNs_base + byt) = pack8(sk[0], sk[1]);
        const float4* s1 = (const float4*)(W1 + (size_t)row * (2 * D) + D + c * 8);
        *(s16x8*)(W1s_base + byt) = pack8abs(s1[0], s1[1]);
        const float4* s2 = (const float4*)(W2 + (size_t)row * (2 * D) + D + c * 8);
        *(s16x8*)(W2s_base + byt) = pack8abs(s2[0], s2[1]);
    }
    __syncthreads();

    // ---- tables GEMM: 32 tiles / 16 waves = 2 (same set+et, kt pair), A hoisted ----
    f32x16 t0acc = {0}, t1acc = {0};
    const int idx0 = 2 * wid;                      // tile ids idx0, idx0+1
    {
        const char* Wsb = (idx0 < 16) ? W1s_base : W2s_base;
        const int er = (((idx0 >> 2) & 3)) * 32 + l31;
        const int eswz = (er & 7) << 4;
        const int kr0 = (idx0 & 3) * 32 + l31;     // idx0&3 in {0,2}
        const int kr1 = kr0 + 32;
        const int kswz = (l31 & 7) << 4;
        #pragma unroll 2
        for (int q = 0; q < 8; ++q) {
            int dby = q * 32 + g32 * 16;
            s16x8 a_ = *(const s16x8*)(Wsb + er * 256 + (dby ^ eswz));
            s16x8 f0 = *(const s16x8*)(KNs_base + kr0 * 256 + (dby ^ kswz));
            s16x8 f1 = *(const s16x8*)(KNs_base + kr1 * 256 + (dby ^ kswz));
            t0acc = __builtin_amdgcn_mfma_f32_32x32x16_bf16(a_, f0, t0acc, 0, 0, 0);
            t1acc = __builtin_amdgcn_mfma_f32_32x32x16_bf16(a_, f1, t1acc, 0, 0, 0);
        }
    }

    // ---- role split: waves 0-7 prep GEMM (e-tile = wid, inline loads);
    //      waves 8-15 PZ.  All loads inline, unroll 1 -> low VGPR pressure;
    //      4 waves/SIMD TLP hides the gather latency. ----
    if (wid < 8) {
        int bl = b0 + l15; bl = bl <= bmax ? bl : bmax;
        const int sid_l = stu_id[bl], eid_l = exer_id[bl];
        const int erow = wid * 16 + l15;
        f32x4 accS = {0, 0, 0, 0}, accE = {0, 0, 0, 0};
        #pragma unroll 1
        for (int q = 0; q < 4; ++q) {
            int d = q * 32 + g16 * 8;
            const float4* pa = (const float4*)(stu_v + (size_t)sid_l * D + d);
            const float4* pe = (const float4*)(exer_v + (size_t)eid_l * D + d);
            const float4* pb = (const float4*)(W1 + (size_t)erow * (2 * D) + d);
            const float4* pc = (const float4*)(W2 + (size_t)erow * (2 * D) + d);
            accS = __builtin_amdgcn_mfma_f32_16x16x32_bf16(
                pack8(pa[0], pa[1]), pack8abs(pb[0], pb[1]), accS, 0, 0, 0);
            accE = __builtin_amdgcn_mfma_f32_16x16x32_bf16(
                pack8(pe[0], pe[1]), pack8abs(pc[0], pc[1]), accE, 0, 0, 0);
        }
        #pragma unroll
        for (int r = 0; r < 4; ++r) {              // lane holds b=g16*4+r, e=erow
            int bi = g16 * 4 + r;
            int eo = bi * 256 + 2 * erow;
            EAf[eo]     = negexp(accS[r]);
            EAf[eo + 1] = negexp(accE[r]);
        }
    } else {
        const int w2 = wid - 8;
        #pragma unroll 1
        for (int rr = 0; rr < 2; ++rr) {           // 2 b-rows per wave
            int r = 2 * w2 + rr;
            int b = b0 + r; b = b <= bmax ? b : bmax;
            int sid = stu_id[b], eid = exer_id[b]; // wave-uniform -> s_load
            float2 sq = *(const float2*)(stu_q + (size_t)sid * D + 2 * lane);
            float2 ek = *(const float2*)(exer_k + (size_t)eid * D + 2 * lane);
            float2 w3 = *(const float2*)(W3 + 2 * lane);
            float2 z;
            z.x = sigf(sq.x * ek.x) * fabsf(w3.x);
            z.y = sigf(sq.y * ek.y) * fabsf(w3.y);
            *(float2*)(PZf + r * D + 2 * lane) = z;
        }
    }
    __syncthreads();   // all staged-LDS reads done -> TAB may overwrite

    TWRITE(idx0, t0acc) TWRITE(idx0 + 1, t1acc)
    __syncthreads();   // TAB/EA/PZ ready

    // ---------------- Phase B: wave owns e in [8*wid, 8*wid+8), lane owns k-pair ----
    const float4* TAB4 = (const float4*)TABf;
    const float4* EA4  = (const float4*)EAf;
    const float2* PZ2  = (const float2*)PZf;

    float2 acc[16];
    #pragma unroll
    for (int r = 0; r < 16; ++r) acc[r] = make_float2(0.f, 0.f);

    #pragma unroll
    for (int jj = 0; jj < 4; ++jj) {
        const int e0 = wid * 8 + 2 * jj;
        const int jg = wid * 4 + jj;
        float4 t0 = TAB4[e0 * 64 + lane];          // per-lane b128
        float4 t1 = TAB4[(e0 + 1) * 64 + lane];
        #pragma unroll
        for (int r = 0; r < 16; ++r) {
            float4 eA = EA4[r * 64 + jg];          // wave-uniform LDS broadcast
            float2 zA = PZ2[r * 64 + jg];
            CORE(eA.x, eA.y, t0, zA.x, acc[r].x, acc[r].y);
            CORE(eA.z, eA.w, t1, zA.y, acc[r].x, acc[r].y);
        }
    }
    __syncthreads();                     // all TAB reads done -> RED may alias

    float2* RED = (float2*)TABf;         // [wave][row][lane] = 128 KB
    #pragma unroll
    for (int r = 0; r < 16; ++r)
        RED[(wid * 16 + r) * 64 + lane] = acc[r];
    __syncthreads();

    // ---- cross-wave reduce + epilogue: wave w handles row w ----
    {
        const int r = wid, b = b0 + r;
        float2 s = make_float2(0.f, 0.f);
        #pragma unroll
        for (int w = 0; w < 16; ++w) {
            float2 p = RED[(w * 16 + r) * 64 + lane];
            s.x += p.x; s.y += p.y;
        }
        const float b3v = b3[0];
        float o0 = sigf(s.x + b3v), o1 = sigf(s.y + b3v);
        float num = 0.f, den = 0.f;
        if (b < B) {
            float2 kqv = *(const float2*)(kq + (size_t)b * D + 2 * lane);
            num = fmaf(o0, kqv.x, o1 * kqv.y); den = kqv.x + kqv.y;
        }
        #pragma unroll
        for (int off = 32; off > 0; off >>= 1) {
            num += __shfl_xor(num, off); den += __shfl_xor(den, off);
        }
        if (lane == 0 && b < B) out[b] = num / den;
    }
}

// ---------------------------------------------------------------------------
extern "C" void kernel_launch(void* const* d_in, const int* in_sizes, int n_in,
                              void* d_out, int out_size, void* d_ws, size_t ws_size,
                              hipStream_t stream)
{
    const int*   stu_id      = (const int*)  d_in[0];
    const int*   exer_id     = (const int*)  d_in[1];
    const float* kq          = (const float*)d_in[2];
    const float* student_q   = (const float*)d_in[3];
    const float* exercise_k  = (const float*)d_in[4];
    const float* student_v   = (const float*)d_in[5];
    const float* exercise_v  = (const float*)d_in[6];
    const float* knowledge_v = (const float*)d_in[7];
    const float* W1 = (const float*)d_in[8];
    const float* b1 = (const float*)d_in[9];
    const float* W2 = (const float*)d_in[10];
    const float* b2 = (const float*)d_in[11];
    const float* W3 = (const float*)d_in[12];
    const float* b3 = (const float*)d_in[13];
    float* out = (float*)d_out;
    const int B = in_sizes[0];

    int nblk = (B + NB - 1) / NB;
    fused_kernel<<<nblk, 1024, 0, stream>>>(
        stu_id, exer_id, kq, student_q, exercise_k, student_v, exercise_v,
        knowledge_v, W1, b1, W2, b2, W3, b3, out, B);
}

// Round 11
// 97.630 us; speedup vs baseline: 1.5619x; 1.5213x over previous
//
#include <hip/hip_runtime.h>

#define D  128   // EMB
#define KN 128   // K_N
#define NB 8     // batch rows per block (grid = 512 -> 2 blocks/CU)
#define LOG2E 1.44269504088896340736f

typedef float f32x4  __attribute__((ext_vector_type(4)));
typedef float f32x16 __attribute__((ext_vector_type(16)));
typedef short s16x8  __attribute__((ext_vector_type(8)));   // 8 bf16 (4 VGPR)

__device__ __forceinline__ float negexp(float v) {              // e^{-v}
    return __builtin_amdgcn_exp2f(v * -LOG2E);
}
__device__ __forceinline__ float sigf(float x) {                // sigmoid
    return __builtin_amdgcn_rcpf(1.0f + negexp(x));
}
__device__ __forceinline__ unsigned short f2bf(float f) {       // fp32->bf16 RNE
    unsigned u = __float_as_uint(f);
    return (unsigned short)((u + 0x7fffu + ((u >> 16) & 1u)) >> 16);
}
__device__ __forceinline__ float bf2f(unsigned short u) {
    return __uint_as_float(((unsigned)u) << 16);
}
__device__ __forceinline__ s16x8 pack8(float4 a, float4 b) {
    s16x8 r;
    r[0]=(short)f2bf(a.x); r[1]=(short)f2bf(a.y); r[2]=(short)f2bf(a.z); r[3]=(short)f2bf(a.w);
    r[4]=(short)f2bf(b.x); r[5]=(short)f2bf(b.y); r[6]=(short)f2bf(b.z); r[7]=(short)f2bf(b.w);
    return r;
}
__device__ __forceinline__ s16x8 pack8abs(float4 a, float4 b) {
    s16x8 r;
    r[0]=(short)f2bf(fabsf(a.x)); r[1]=(short)f2bf(fabsf(a.y)); r[2]=(short)f2bf(fabsf(a.z)); r[3]=(short)f2bf(fabsf(a.w));
    r[4]=(short)f2bf(fabsf(b.x)); r[5]=(short)f2bf(fabsf(b.y)); r[6]=(short)f2bf(fabsf(b.z)); r[7]=(short)f2bf(fabsf(b.w));
    return r;
}

// phase-B core: 2 elements (k=2l,2l+1) of one (b,e)
#define CORE(EA1, EA2, T, PZ, A0, A1) do {                                   \
    float x0_ = fmaf((EA1), (T).x, 1.0f);                                    \
    float x1_ = fmaf((EA1), (T).y, 1.0f);                                    \
    float y0_ = fmaf((EA2), (T).z, 1.0f);                                    \
    float y1_ = fmaf((EA2), (T).w, 1.0f);                                    \
    (A0) = fmaf((y0_ - x0_) * (PZ), __builtin_amdgcn_rcpf(x0_ * y0_), (A0)); \
    (A1) = fmaf((y1_ - x1_) * (PZ), __builtin_amdgcn_rcpf(x1_ * y1_), (A1)); \
} while (0)

// tables write: bf16(exp(-(acc+bias))) into interleaved TAB layout
//   TABh[e*256 + (k>>1)*4 + (k&1) + (0|2)]   (32x32 C-layout per m74)
#define TWRITE(IDX, ACC) {                                                    \
    const int slot_ = ((IDX) < 16) ? 0 : 2;                                   \
    const float* bias_ = ((IDX) < 16) ? b1 : b2;                              \
    const int k_ = ((IDX) & 3) * 32 + l31;                                    \
    const int kof_ = ((k_ >> 1) << 2) + (k_ & 1) + slot_;                     \
    _Pragma("unroll")                                                         \
    for (int r = 0; r < 16; ++r) {                                            \
        int e_ = (((IDX) >> 2) & 3) * 32 + (r & 3) + ((r >> 2) << 3) + (g32 << 2); \
        TABh[e_ * 256 + kof_] = f2bf(negexp(ACC[r] + bias_[e_]));             \
    } }

__global__ __launch_bounds__(512, 4) void fused_kernel(
    const int* __restrict__ stu_id, const int* __restrict__ exer_id,
    const float* __restrict__ kq,
    const float* __restrict__ stu_q, const float* __restrict__ exer_k,
    const float* __restrict__ stu_v, const float* __restrict__ exer_v,
    const float* __restrict__ kn,
    const float* __restrict__ W1, const float* __restrict__ b1,
    const float* __restrict__ W2, const float* __restrict__ b2,
    const float* __restrict__ W3, const float* __restrict__ b3,
    float* __restrict__ out, int B)
{
    // LDS map (77824 B -> 2 blocks/CU):
    //   [0,65536)        TAB bf16 ushort4[e][lane] = {E1(2l),E1(2l+1),E2(2l),E2(2l+1)}
    //                    phase A alias: KNs bf16 staged rows [0,32768)
    //                    epilogue alias: RED float2[8][8][64] = 32 KB
    //   [65536,73728)    EAf fp32: b*256 + 2e + {0,1}
    //   [73728,77824)    PZf fp32: r*128 + e
    __shared__ __align__(16) char smemraw[77824];
    __shared__ int sids[NB], eids[NB];

    unsigned short* TABh  = (unsigned short*)smemraw;
    const ushort4*  TABh4 = (const ushort4*)smemraw;
    char*  KNs_base = smemraw;
    float* EAf = (float*)(smemraw + 65536);
    float* PZf = (float*)(smemraw + 73728);

    const int tid  = threadIdx.x;
    const int b0   = blockIdx.x * NB;
    const int lane = tid & 63, wid = tid >> 6;     // 8 waves
    const int l31 = lane & 31, g32 = lane >> 5;
    const int l15 = lane & 15, g16 = lane >> 4;
    const int bmax = B - 1;

    if (tid < NB) {
        int b = b0 + tid;
        sids[tid] = stu_id[b <= bmax ? b : bmax];
        eids[tid] = exer_id[b <= bmax ? b : bmax];
    }
    // ---- stage kn as bf16 (pack once), row 256B, XOR-swizzled ----
    for (int i = tid; i < 128 * 16; i += 512) {    // 4 iters/thread
        int row = i >> 4, c = i & 15;
        int byt = row * 256 + (((c << 4)) ^ ((row & 7) << 4));
        const float4* sk = (const float4*)(kn + (size_t)row * D + c * 8);
        *(s16x8*)(KNs_base + byt) = pack8(sk[0], sk[1]);
    }
    __syncthreads();

    // ---- tables GEMM: wave = (set = wid<4 ? W1:W2, et = wid&3), kt 0-3 ----
    //      A (|W|) packed inline from global (8 packs/wave); B (kn) from LDS.
    f32x16 t0acc = {0}, t1acc = {0}, t2acc = {0}, t3acc = {0};
    {
        const float* Wt = (wid < 4) ? W1 : W2;
        const int er = (wid & 3) * 32 + l31;
        const int kswz = (l31 & 7) << 4;
        #pragma unroll 2
        for (int q = 0; q < 8; ++q) {
            int del = q * 16 + g32 * 8;            // fp32 elem offset in W row
            int dby = q * 32 + g32 * 16;           // byte offset in staged kn row
            const float4* pw = (const float4*)(Wt + (size_t)er * (2 * D) + D + del);
            s16x8 a_ = pack8abs(pw[0], pw[1]);
            s16x8 f0 = *(const s16x8*)(KNs_base + (  0 + l31) * 256 + (dby ^ kswz));
            s16x8 f1 = *(const s16x8*)(KNs_base + ( 32 + l31) * 256 + (dby ^ kswz));
            s16x8 f2 = *(const s16x8*)(KNs_base + ( 64 + l31) * 256 + (dby ^ kswz));
            s16x8 f3 = *(const s16x8*)(KNs_base + ( 96 + l31) * 256 + (dby ^ kswz));
            t0acc = __builtin_amdgcn_mfma_f32_32x32x16_bf16(a_, f0, t0acc, 0, 0, 0);
            t1acc = __builtin_amdgcn_mfma_f32_32x32x16_bf16(a_, f1, t1acc, 0, 0, 0);
            t2acc = __builtin_amdgcn_mfma_f32_32x32x16_bf16(a_, f2, t2acc, 0, 0, 0);
            t3acc = __builtin_amdgcn_mfma_f32_32x32x16_bf16(a_, f3, t3acc, 0, 0, 0);
        }
    }
    __syncthreads();   // all KNs reads done -> TAB may overwrite [0,32K)

    // ---- TWRITE first: kills the 64 acc regs before prep GEMM ----
    {
        const int idx0 = 4 * wid;
        TWRITE(idx0 + 0, t0acc) TWRITE(idx0 + 1, t1acc)
        TWRITE(idx0 + 2, t2acc) TWRITE(idx0 + 3, t3acc)
    }

    // ---- prep GEMM: C[8b x 16e], e-tile = wid; A rows 8-15 are dup of 0-7 ----
    {
        const int bi = l15 & 7;
        const int sid_l = sids[bi], eid_l = eids[bi];
        const int erow = wid * 16 + l15;
        f32x4 accS = {0, 0, 0, 0}, accE = {0, 0, 0, 0};
        #pragma unroll 1
        for (int q = 0; q < 4; ++q) {
            int d = q * 32 + g16 * 8;
            const float4* pa = (const float4*)(stu_v + (size_t)sid_l * D + d);
            const float4* pe = (const float4*)(exer_v + (size_t)eid_l * D + d);
            const float4* pb = (const float4*)(W1 + (size_t)erow * (2 * D) + d);
            const float4* pc = (const float4*)(W2 + (size_t)erow * (2 * D) + d);
            accS = __builtin_amdgcn_mfma_f32_16x16x32_bf16(
                pack8(pa[0], pa[1]), pack8abs(pb[0], pb[1]), accS, 0, 0, 0);
            accE = __builtin_amdgcn_mfma_f32_16x16x32_bf16(
                pack8(pe[0], pe[1]), pack8abs(pc[0], pc[1]), accE, 0, 0, 0);
        }
        #pragma unroll
        for (int r = 0; r < 4; ++r) {              // C row = g16*4+r, col e = erow
            int brow = g16 * 4 + r;
            if (brow < NB) {
                int eo = brow * 256 + 2 * erow;
                EAf[eo]     = negexp(accS[r]);
                EAf[eo + 1] = negexp(accE[r]);
            }
        }
    }
    // ---- PZ: wave w handles row w ----
    {
        const int r = wid;
        int b = b0 + r; b = b <= bmax ? b : bmax;
        const int sid = stu_id[b], eid = exer_id[b];   // wave-uniform
        float2 sq = *(const float2*)(stu_q + (size_t)sid * D + 2 * lane);
        float2 ek = *(const float2*)(exer_k + (size_t)eid * D + 2 * lane);
        float2 w3 = *(const float2*)(W3 + 2 * lane);
        float2 z;
        z.x = sigf(sq.x * ek.x) * fabsf(w3.x);
        z.y = sigf(sq.y * ek.y) * fabsf(w3.y);
        *(float2*)(PZf + r * D + 2 * lane) = z;
    }
    __syncthreads();   // TAB/EA/PZ ready

    // ---------------- Phase B: wave owns e in [16w,16w+16), lane owns k-pair ----
    const float4* EA4 = (const float4*)EAf;
    const float2* PZ2 = (const float2*)PZf;

    float2 acc[NB];
    #pragma unroll
    for (int r = 0; r < NB; ++r) acc[r] = make_float2(0.f, 0.f);

    #pragma unroll
    for (int jj = 0; jj < 8; ++jj) {
        const int e0 = wid * 16 + 2 * jj;
        const int j  = wid * 8 + jj;
        ushort4 h0 = TABh4[e0 * 64 + lane];        // b64 LDS read
        ushort4 h1 = TABh4[(e0 + 1) * 64 + lane];
        float4 t0 = make_float4(bf2f(h0.x), bf2f(h0.y), bf2f(h0.z), bf2f(h0.w));
        float4 t1 = make_float4(bf2f(h1.x), bf2f(h1.y), bf2f(h1.z), bf2f(h1.w));
        #pragma unroll
        for (int r = 0; r < NB; ++r) {
            float4 eA = EA4[r * 64 + j];           // wave-uniform LDS broadcast
            float2 zA = PZ2[r * 64 + j];
            CORE(eA.x, eA.y, t0, zA.x, acc[r].x, acc[r].y);
            CORE(eA.z, eA.w, t1, zA.y, acc[r].x, acc[r].y);
        }
    }
    __syncthreads();                     // all TAB reads done -> RED may alias

    float2* RED = (float2*)smemraw;      // [wave][row][lane] = 32 KB
    #pragma unroll
    for (int r = 0; r < NB; ++r)
        RED[(wid * NB + r) * 64 + lane] = acc[r];
    __syncthreads();

    // ---- cross-wave reduce + epilogue: wave w handles row w ----
    {
        const int r = wid, b = b0 + r;
        float2 s = make_float2(0.f, 0.f);
        #pragma unroll
        for (int w = 0; w < 8; ++w) {
            float2 p = RED[(w * NB + r) * 64 + lane];
            s.x += p.x; s.y += p.y;
        }
        const float b3v = b3[0];
        float o0 = sigf(s.x + b3v), o1 = sigf(s.y + b3v);
        float num = 0.f, den = 0.f;
        if (b < B) {
            float2 kqv = *(const float2*)(kq + (size_t)b * D + 2 * lane);
            num = fmaf(o0, kqv.x, o1 * kqv.y); den = kqv.x + kqv.y;
        }
        #pragma unroll
        for (int off = 32; off > 0; off >>= 1) {
            num += __shfl_xor(num, off); den += __shfl_xor(den, off);
        }
        if (lane == 0 && b < B) out[b] = num / den;
    }
}

// ---------------------------------------------------------------------------
extern "C" void kernel_launch(void* const* d_in, const int* in_sizes, int n_in,
                              void* d_out, int out_size, void* d_ws, size_t ws_size,
                              hipStream_t stream)
{
    const int*   stu_id      = (const int*)  d_in[0];
    const int*   exer_id     = (const int*)  d_in[1];
    const float* kq          = (const float*)d_in[2];
    const float* student_q   = (const float*)d_in[3];
    const float* exercise_k  = (const float*)d_in[4];
    const float* student_v   = (const float*)d_in[5];
    const float* exercise_v  = (const float*)d_in[6];
    const float* knowledge_v = (const float*)d_in[7];
    const float* W1 = (const float*)d_in[8];
    const float* b1 = (const float*)d_in[9];
    const float* W2 = (const float*)d_in[10];
    const float* b2 = (const float*)d_in[11];
    const float* W3 = (const float*)d_in[12];
    const float* b3 = (const float*)d_in[13];
    float* out = (float*)d_out;
    const int B = in_sizes[0];

    int nblk = (B + NB - 1) / NB;
    fused_kernel<<<nblk, 512, 0, stream>>>(
        stu_id, exer_id, kq, student_q, exercise_k, student_v, exercise_v,
        knowledge_v, W1, b1, W2, b2, W3, b3, out, B);
}